// Round 19
// baseline (13447.580 us; speedup 1.0000x reference)
//
#include <hip/hip_runtime.h>
#include <cstdint>
#include <cstddef>

#define TT 514
#define DIR_WGS 64
#define SCAN_WGS 128
#define SCAN_THR 512

typedef unsigned short u16;
typedef unsigned long long u64;
typedef short short8 __attribute__((ext_vector_type(8)));
typedef float f32x4 __attribute__((ext_vector_type(4)));

__device__ __forceinline__ float bf2f(u16 u) {
  union { unsigned i; float f; } x; x.i = ((unsigned)u) << 16; return x.f;
}
__device__ __forceinline__ u16 f2bf(float f) {
  union { float f; unsigned i; } x; x.f = f;
  unsigned r = x.i + 0x7fffu + ((x.i >> 16) & 1u);
  return (u16)(r >> 16);
}
__device__ __forceinline__ float sigm(float x) { return 1.f / (1.f + expf(-x)); }
__device__ __forceinline__ f32x4 mfma16(short8 a, short8 b, f32x4 c) {
  return __builtin_amdgcn_mfma_f32_16x16x32_bf16(a, b, c, 0, 0, 0);
}
__device__ __forceinline__ void sb_set(float* sb, int k) {
  __hip_atomic_store(sb + k, 1.0f, __ATOMIC_RELAXED, __HIP_MEMORY_SCOPE_AGENT);
}

// distributed flag wait: lane l ACQUIRE-polls flags[l] (64 flags, 4 cachelines,
// parallel). Monotonic flags (= step+1). Dead check off the fast path.
__device__ __forceinline__ void wait_flags(int* flags, int target, int* dead) {
  if (threadIdx.x < 64) {
    int spins = 0;
    while (__hip_atomic_load(flags + threadIdx.x, __ATOMIC_ACQUIRE,
                             __HIP_MEMORY_SCOPE_AGENT) < target) {
      __builtin_amdgcn_s_sleep(1);
      if (((++spins) & 0xFFFF) == 0) {
        if (spins > (1 << 22) ||
            __hip_atomic_load(dead, __ATOMIC_RELAXED, __HIP_MEMORY_SCOPE_AGENT) != 0) {
          __hip_atomic_store(dead, 1, __ATOMIC_RELAXED, __HIP_MEMORY_SCOPE_AGENT);
          break;
        }
      }
    }
  }
  __syncthreads();
}

// ---- diagnostics (f32, visible) ----
__global__ void diag_kernel(float* __restrict__ out, float code, int slot) {
  if (threadIdx.x == 0 && blockIdx.x == 0) out[slot] = code;
}
__global__ void verify_kernel(const float* __restrict__ sb, const int* __restrict__ sync,
                              float* __restrict__ out) {
  if (threadIdx.x == 0 && blockIdx.x == 0) {
    for (int k = 0; k < 6; ++k) {
      float v = __hip_atomic_load(sb + k, __ATOMIC_RELAXED, __HIP_MEMORY_SCOPE_AGENT);
      if (v != 1.0f) out[9 + k] = 4096.f + (float)k * 256.f;
    }
    for (int l = 0; l < 2; ++l)
      for (int d = 0; d < 2; ++d)
        if (sync[l * 512 + d * 256 + 128] != 0)
          out[8] = 8192.f + (float)(l * 2 + d) * 256.f;
  }
}

// ---------------- embedding + BOS/EOS -> x bf16, layout [t][b][d] ----------------
__global__ __launch_bounds__(256) void embed_kernel(const int* __restrict__ words,
                                                    const float* __restrict__ E,
                                                    const float* __restrict__ bos,
                                                    const float* __restrict__ eos,
                                                    u16* __restrict__ xb16,
                                                    float* __restrict__ sb) {
  int bid = blockIdx.x;           // t*4 + b
  int t = bid >> 2, b = bid & 3;
  const float* src;
  if (t == 0) src = bos;
  else if (t == TT - 1) src = eos;
  else { int v = words[b * 512 + (t - 1)]; src = E + (size_t)v * 512; }
  for (int i = threadIdx.x; i < 512; i += 256)
    xb16[(size_t)bid * 512 + i] = f2bf(src[i]);
  if (bid == TT * 4 - 1 && threadIdx.x == 0) sb_set(sb, 0);
}

// ---- XW[dir][t*4+b][16384] = (x @ W_in + bias), bf16. K=512, M=2056, N=16384 ----
__global__ __launch_bounds__(256) void xw_gemm(const u16* __restrict__ Af,
                                               const u16* __restrict__ Ab,
                                               const float* __restrict__ Win_g,
                                               const float* __restrict__ bias_g,
                                               u16* __restrict__ XW,
                                               float* __restrict__ sb,
                                               int layer, int sbslot) {
  int bid = blockIdx.x;
  int dir = bid / (17 * 128);
  int rem = bid % (17 * 128);
  int mb = rem / 128, nb = rem % 128;
  const u16* A = dir ? Ab : Af;
  const float* B = Win_g + (size_t)(dir * 2 + layer) * 512 * 16384;
  const float* bias = bias_g + (size_t)(dir * 2 + layer) * 16384;
  u16* out = XW + (size_t)dir * 2056 * 16384;
  int m0 = mb * 128, n0 = nb * 128;
  __shared__ char lds[2 * 128 * 80];
  char* At = lds;
  char* Bt = lds + 128 * 80;
  int tid = threadIdx.x, wv = tid >> 6, ln = tid & 63;
  int wr = wv >> 1, wc = wv & 1;
  f32x4 acc[4][4];
  #pragma unroll
  for (int i = 0; i < 4; ++i)
    #pragma unroll
    for (int j = 0; j < 4; ++j) acc[i][j] = (f32x4){0.f, 0.f, 0.f, 0.f};
  for (int k0 = 0; k0 < 512; k0 += 32) {
    __syncthreads();
    {
      int r = tid >> 2, kq = (tid & 3) * 8;
      for (int rr = r; rr < 128; rr += 64) {
        int grow = m0 + rr; if (grow >= 2056) grow = 2055;
        short8 va = *(const short8*)(A + (size_t)grow * 512 + k0 + kq);
        *(short8*)(At + rr * 80 + kq * 2) = va;
      }
      int kk = tid >> 3, nq = (tid & 7) * 16;
      const float* bp = B + (size_t)(k0 + kk) * 16384 + n0 + nq;
      #pragma unroll
      for (int e = 0; e < 16; ++e)
        *(u16*)(Bt + (nq + e) * 80 + kk * 2) = f2bf(bp[e]);
    }
    __syncthreads();
    int lr = ln & 15, kq2 = (ln >> 4) * 8;
    short8 af[4], bf[4];
    #pragma unroll
    for (int i = 0; i < 4; ++i) {
      af[i] = *(const short8*)(At + (wr * 64 + i * 16 + lr) * 80 + kq2 * 2);
      bf[i] = *(const short8*)(Bt + (wc * 64 + i * 16 + lr) * 80 + kq2 * 2);
    }
    #pragma unroll
    for (int i = 0; i < 4; ++i)
      #pragma unroll
      for (int j = 0; j < 4; ++j) acc[i][j] = mfma16(af[i], bf[j], acc[i][j]);
  }
  int cc = ln & 15, rq = (ln >> 4) * 4;
  #pragma unroll
  for (int i = 0; i < 4; ++i)
    #pragma unroll
    for (int j = 0; j < 4; ++j) {
      int m = m0 + wr * 64 + i * 16 + rq;
      int v = n0 + wc * 64 + j * 16 + cc;
      float bv = bias[v];
      #pragma unroll
      for (int r2 = 0; r2 < 4; ++r2)
        if (m + r2 < 2056) out[(size_t)(m + r2) * 16384 + v] = f2bf(acc[i][j][r2] + bv);
    }
  if (bid == 2 * 17 * 128 - 1 && tid == 0) sb_set(sb, sbslot);
}

// ---------------- persistent bidirectional LSTM scan v19 (r18 + MLP reduce) ----------------
// 128 WGs x 512 thr. dir = wg>>6, wgd = wg&63 owns channels [wgd*64,+64).
// per step: gates (h LOCAL) -> a -> partial proj -> publish contiguous 4KB + flag ->
//   ONE wait -> reduce slot-pair (2t,2t+1): 64 u64 loads, 8 ILP chains, wgd-staggered w.
__global__ __launch_bounds__(SCAN_THR, 2) void scan_kernel(
    const float* __restrict__ Wst_g, const float* __restrict__ Wp_g,
    const u16* __restrict__ XW, u16* __restrict__ sob_f, u16* __restrict__ sob_b,
    unsigned* __restrict__ pbuf, int* __restrict__ sync, float* __restrict__ sb,
    int layer, int sbslot) {
  __shared__ u16 h_lds[4][520];          // stride 1040 B, local h (bf16)
  __shared__ float gates_lds[256][4];    // [col][b]
  __shared__ u16 a_loc[4][64];           // [b][ch] own channels
  int tid = threadIdx.x, ln = tid & 63;
  int wv = tid >> 6, l15 = ln & 15, lq = ln >> 4;
  int dir = (int)blockIdx.x >> 6, wgd = (int)blockIdx.x & 63;
  int dl = dir * 2 + layer;
  const float* Wst = Wst_g + (size_t)dl * 512 * 16384;
  const float* Wp  = Wp_g  + (size_t)dl * 4096 * 512;
  const u16* xw = XW + (size_t)dir * 2056 * 16384;
  u16* sob = dir ? sob_b : sob_f;
  int* pflags = sync + dir * 256;
  int* dead = pflags + 128;

  // W_state frags: 2 col-tiles x 16 k-tiles (this WG's 256 gate-cols)
  short8 wst[2][16];
  #pragma unroll
  for (int ct = 0; ct < 2; ++ct) {
    int colL = wv * 32 + ct * 16 + l15;
    int gcol = (colL >> 6) * 4096 + wgd * 64 + (colL & 63);
    #pragma unroll
    for (int kt = 0; kt < 16; ++kt) {
      short8 f;
      #pragma unroll
      for (int e = 0; e < 8; ++e)
        ((u16*)&f)[e] = f2bf(Wst[(size_t)(kt * 32 + lq * 8 + e) * 16384 + gcol]);
      wst[ct][kt] = f;
    }
  }
  // W_proj frags: own 64 channels (K=64, 2 k-tiles) x wave's 4 col-tiles (cols wv*64..+64)
  short8 wpf[4][2];
  #pragma unroll
  for (int ct = 0; ct < 4; ++ct) {
    #pragma unroll
    for (int kt = 0; kt < 2; ++kt) {
      short8 f;
      #pragma unroll
      for (int e = 0; e < 8; ++e)
        ((u16*)&f)[e] = f2bf(Wp[(size_t)(wgd * 64 + kt * 32 + lq * 8 + e) * 512 +
                                wv * 64 + ct * 16 + l15]);
      wpf[ct][kt] = f;
    }
  }
  float cst = 0.f;                       // c-state (tid<256): ch=tid>>2, b=tid&3
  int ew_ch = tid >> 2, ew_b = tid & 3;

  // zero local h(-1)
  for (int i = tid; i < 1040; i += SCAN_THR)
    *(unsigned*)((char*)h_lds + (i >> 8) * 1040 + (i & 255) * 4) = 0u;   // covers [4][512]

  // prefetch XW for step 0
  float xw0 = 0.f, xw1 = 0.f, xw2 = 0.f, xw3 = 0.f;
  if (tid < 256) {
    int t0 = dir ? (TT - 1) : 0;
    size_t xb0 = ((size_t)t0 * 4 + ew_b) * 16384 + wgd * 64 + ew_ch;
    xw0 = bf2f(xw[xb0]);        xw1 = bf2f(xw[xb0 + 4096]);
    xw2 = bf2f(xw[xb0 + 8192]); xw3 = bf2f(xw[xb0 + 12288]);
  }
  __syncthreads();

  for (int s = 0; s < TT; ++s) {
    int t = dir ? (TT - 1 - s) : s;
    // ---- P1: gates MFMA (h local in LDS) ----
    f32x4 g0 = {0.f, 0.f, 0.f, 0.f}, g1 = {0.f, 0.f, 0.f, 0.f};
    #pragma unroll
    for (int kt = 0; kt < 16; ++kt) {
      short8 hf = *(const short8*)((const char*)h_lds + (ln & 3) * 1040 + lq * 16 + kt * 64);
      g0 = mfma16(hf, wst[0][kt], g0);
      g1 = mfma16(hf, wst[1][kt], g1);
    }
    if (ln < 16) {
      #pragma unroll
      for (int r = 0; r < 4; ++r) {
        gates_lds[wv * 32 + l15][r] = g0[r];
        gates_lds[wv * 32 + 16 + l15][r] = g1[r];
      }
    }
    __syncthreads();
    // ---- P2: elementwise (prefetched XW) -> a (own 64 ch) ----
    if (tid < 256) {
      float gi = gates_lds[0 * 64 + ew_ch][ew_b] + xw0;
      float gf = gates_lds[1 * 64 + ew_ch][ew_b] + xw1;
      float gg = gates_lds[2 * 64 + ew_ch][ew_b] + xw2;
      float go = gates_lds[3 * 64 + ew_ch][ew_b] + xw3;
      float cn = sigm(gi) * tanhf(gg) + sigm(gf) * cst;
      cn = fminf(3.f, fmaxf(-3.f, cn));
      cst = cn;
      a_loc[ew_b][ew_ch] = f2bf(sigm(go) * tanhf(cn));
    }
    __syncthreads();
    // ---- P3: partial projection a[4x64] @ Wp[64x512] -> bf16 partials -> publish ----
    unsigned* pb = pbuf + (((s & 1) * 2) + dir) * 65536;   // [parity][dir][64wg][1024]
    {
      f32x4 pa[4];
      #pragma unroll
      for (int ct = 0; ct < 4; ++ct) {
        pa[ct] = (f32x4){0.f, 0.f, 0.f, 0.f};
        #pragma unroll
        for (int kt = 0; kt < 2; ++kt) {
          short8 af = *(const short8*)((const char*)a_loc + (ln & 3) * 128 + kt * 64 + lq * 16);
          pa[ct] = mfma16(af, wpf[ct][kt], pa[ct]);
        }
      }
      // D layout: col = wv*64 + ct*16 + (ln&15), rows 0..3 = regs (ln<16)
      unsigned* myp = pb + wgd * 1024;
      #pragma unroll
      for (int ct = 0; ct < 4; ++ct)
        #pragma unroll
        for (int r = 0; r < 4; ++r) {
          int pv = (int)f2bf(pa[ct][r]);
          int qv = __shfl_down(pv, 1, 64);   // neighbor col
          if (ln < 16 && (ln & 1) == 0) {
            int cp = (wv * 64 + ct * 16 + ln) >> 1;   // col-pair 0..255
            __hip_atomic_store(myp + r * 256 + cp,
                               (unsigned)(pv & 0xFFFF) | ((unsigned)qv << 16),
                               __ATOMIC_RELAXED, __HIP_MEMORY_SCOPE_AGENT);
          }
        }
    }
    __syncthreads();   // drain partial stores before flag
    if (tid == 0)
      __hip_atomic_store(pflags + wgd, s + 1, __ATOMIC_RELEASE, __HIP_MEMORY_SCOPE_AGENT);
    // prefetch XW for s+1 (independent; hides L3 latency under wait+reduce)
    if (s + 1 < TT && tid < 256) {
      int t1 = dir ? (TT - 2 - s) : (s + 1);
      size_t xb1 = ((size_t)t1 * 4 + ew_b) * 16384 + wgd * 64 + ew_ch;
      xw0 = bf2f(xw[xb1]);        xw1 = bf2f(xw[xb1 + 4096]);
      xw2 = bf2f(xw[xb1 + 8192]); xw3 = bf2f(xw[xb1 + 12288]);
    }
    // ---- P4: ONE wait, then reduce slot-pair (2t,2t+1): 8 ILP chains, staggered w ----
    wait_flags(pflags, s + 1, dead);
    {
      const u64* src64 = (const u64*)pb;   // u64 idx w*512 + tid
      float lo0a = 0.f, hi0a = 0.f, lo1a = 0.f, hi1a = 0.f;
      float lo0b = 0.f, hi0b = 0.f, lo1b = 0.f, hi1b = 0.f;
      #pragma unroll 16
      for (int w0 = 0; w0 < 64; w0 += 2) {
        int wA = (w0 + wgd) & 63;
        int wB = (w0 + 1 + wgd) & 63;
        u64 va = __hip_atomic_load(src64 + wA * 512 + tid, __ATOMIC_RELAXED,
                                   __HIP_MEMORY_SCOPE_AGENT);
        u64 vb = __hip_atomic_load(src64 + wB * 512 + tid, __ATOMIC_RELAXED,
                                   __HIP_MEMORY_SCOPE_AGENT);
        unsigned a0 = (unsigned)va, a1 = (unsigned)(va >> 32);
        unsigned b0 = (unsigned)vb, b1 = (unsigned)(vb >> 32);
        lo0a += bf2f((u16)(a0 & 0xFFFF));
        hi0a += bf2f((u16)(a0 >> 16));
        lo1a += bf2f((u16)(a1 & 0xFFFF));
        hi1a += bf2f((u16)(a1 >> 16));
        lo0b += bf2f((u16)(b0 & 0xFFFF));
        hi0b += bf2f((u16)(b0 >> 16));
        lo1b += bf2f((u16)(b1 & 0xFFFF));
        hi1b += bf2f((u16)(b1 >> 16));
      }
      float lo0 = lo0a + lo0b, hi0 = hi0a + hi0b;
      float lo1 = lo1a + lo1b, hi1 = hi1a + hi1b;
      lo0 = fminf(3.f, fmaxf(-3.f, lo0));
      hi0 = fminf(3.f, fmaxf(-3.f, hi0));
      lo1 = fminf(3.f, fmaxf(-3.f, lo1));
      hi1 = fminf(3.f, fmaxf(-3.f, hi1));
      unsigned pk0 = (unsigned)f2bf(lo0) | ((unsigned)f2bf(hi0) << 16);
      unsigned pk1 = (unsigned)f2bf(lo1) | ((unsigned)f2bf(hi1) << 16);
      u64 pk = (u64)pk0 | ((u64)pk1 << 32);
      int q = tid * 2;                    // slots q, q+1: b = q>>8, cp = q&255 (even)
      int b = q >> 8, cp = q & 255;
      *(u64*)((char*)h_lds + b * 1040 + cp * 4) = pk;
      if (wgd == 0)
        *(u64*)(sob + ((size_t)t * 4 + b) * 512 + cp * 2) = pk;
    }
    __syncthreads();   // h(s) complete before next gates
  }
  if ((int)blockIdx.x == SCAN_WGS - 1 && tid == 0) sb_set(sb, sbslot);
}

// ------- softmax-weight mixing -> f32 output + bf16 logit A (tied=[E;E] K-fold) -------
__global__ __launch_bounds__(256) void mix_kernel(const u16* __restrict__ xb,
                                                  const u16* __restrict__ s1f,
                                                  const u16* __restrict__ s1b,
                                                  const u16* __restrict__ s2f,
                                                  const u16* __restrict__ s2b,
                                                  const float* __restrict__ sv,
                                                  const float* __restrict__ gm,
                                                  float* __restrict__ out,
                                                  u16* __restrict__ logitA,
                                                  float* __restrict__ sb) {
  int m = blockIdx.x;             // b*512 + tt
  int b = m >> 9, tt = m & 511;
  int t = tt + 1;
  float v0s = sv[0], v1s = sv[1], v2s = sv[2];
  float mx = fmaxf(v0s, fmaxf(v1s, v2s));
  float e0 = expf(v0s - mx), e1 = expf(v1s - mx), e2 = expf(v2s - mx);
  float inv = 1.f / (e0 + e1 + e2);
  float w0 = e0 * inv, w1 = e1 * inv, w2 = e2 * inv;
  float g = gm[0];
  size_t base = ((size_t)t * 4 + b) * 512;
  for (int d = threadIdx.x; d < 512; d += 256) {
    float xv = bf2f(xb[base + d]);
    float a1f = bf2f(s1f[base + d]), a1b = bf2f(s1b[base + d]);
    float a2f = bf2f(s2f[base + d]), a2b = bf2f(s2b[base + d]);
    float o0 = g * (w0 * xv + w1 * a1f + w2 * (a2f + a1f));  // layer2 = raw + layer1 resid
    float o1 = g * (w0 * xv + w1 * a1b + w2 * (a2b + a1b));
    out[(size_t)m * 1024 + d] = o0;
    out[(size_t)m * 1024 + 512 + d] = o1;
    logitA[(size_t)m * 512 + d] = f2bf(o0 + o1);
  }
  if (m == 2047 && threadIdx.x == 0) sb_set(sb, 5);
}

__global__ __launch_bounds__(256) void mask_fill(float* __restrict__ out) {
  int i = blockIdx.x * 256 + threadIdx.x;
  if (i < 2048) out[2097152 + i] = 1.0f;
}

// ---- logit GEMM: C[2048][32000](f32) = A[2048][512](bf16) * E[32000][512](f32->bf16)^T ----
__global__ __launch_bounds__(256) void logit_gemm(const u16* __restrict__ A,
                                                  const float* __restrict__ E,
                                                  float* __restrict__ out) {
  int bid = blockIdx.x;
  int mb = bid / 250, nb = bid % 250;
  int m0 = mb * 128, n0 = nb * 128;
  __shared__ char lds[2 * 128 * 80];
  char* At = lds;
  char* Bt = lds + 128 * 80;
  int tid = threadIdx.x, wv = tid >> 6, ln = tid & 63;
  int wr = wv >> 1, wc = wv & 1;
  f32x4 acc[4][4];
  #pragma unroll
  for (int i = 0; i < 4; ++i)
    #pragma unroll
    for (int j = 0; j < 4; ++j) acc[i][j] = (f32x4){0.f, 0.f, 0.f, 0.f};
  for (int k0 = 0; k0 < 512; k0 += 32) {
    __syncthreads();
    int r = tid >> 2, kq = (tid & 3) * 8;
    for (int rr = r; rr < 128; rr += 64) {
      short8 va = *(const short8*)(A + (size_t)(m0 + rr) * 512 + k0 + kq);
      *(short8*)(At + rr * 80 + kq * 2) = va;
      const float* ep = E + (size_t)(n0 + rr) * 512 + k0 + kq;
      float4 ea = *(const float4*)ep;
      float4 eb = *(const float4*)(ep + 4);
      short8 vb;
      ((u16*)&vb)[0] = f2bf(ea.x); ((u16*)&vb)[1] = f2bf(ea.y);
      ((u16*)&vb)[2] = f2bf(ea.z); ((u16*)&vb)[3] = f2bf(ea.w);
      ((u16*)&vb)[4] = f2bf(eb.x); ((u16*)&vb)[5] = f2bf(eb.y);
      ((u16*)&vb)[6] = f2bf(eb.z); ((u16*)&vb)[7] = f2bf(eb.w);
      *(short8*)(Bt + rr * 80 + kq * 2) = vb;
    }
    __syncthreads();
    int lr = ln & 15, kq2 = (ln >> 4) * 8;
    short8 af[4], bf[4];
    #pragma unroll
    for (int i = 0; i < 4; ++i) {
      af[i] = *(const short8*)(At + (wr * 64 + i * 16 + lr) * 80 + kq2 * 2);
      bf[i] = *(const short8*)(Bt + (wc * 64 + i * 16 + lr) * 80 + kq2 * 2);
    }
    #pragma unroll
    for (int i = 0; i < 4; ++i)
      #pragma unroll
      for (int j = 0; j < 4; ++j) acc[i][j] = mfma16(af[i], bf[j], acc[i][j]);
  }
  int cc = ln & 15, rq = (ln >> 4) * 4;
  #pragma unroll
  for (int i = 0; i < 4; ++i)
    #pragma unroll
    for (int j = 0; j < 4; ++j) {
      int m = m0 + wr * 64 + i * 16 + rq;
      int v = n0 + wc * 64 + j * 16 + cc;
      #pragma unroll
      for (int r2 = 0; r2 < 4; ++r2)
        out[2099200 + (size_t)(m + r2) * 32000 + v] = acc[i][j][r2];
    }
}

static int map_hip_err(hipError_t e) {
  switch ((int)e) {
    case 1: return 1;
    case 2: return 2;
    case 9: return 3;
    case 98: return 4;
    case 701: return 5;
    case 719: return 6;
    case 720: return 7;
    default: return 0;
  }
}

extern "C" void kernel_launch(void* const* d_in, const int* in_sizes, int n_in,
                              void* d_out, int out_size, void* d_ws, size_t ws_size,
                              hipStream_t stream) {
  const int* words = (const int*)d_in[0];
  const float* E = (const float*)d_in[1];
  const float* bos = (const float*)d_in[2];
  const float* eos = (const float*)d_in[3];
  const float* Win = (const float*)d_in[4];
  const float* Wst = (const float*)d_in[5];
  const float* bias = (const float*)d_in[6];
  const float* Wp = (const float*)d_in[7];
  const float* sv = (const float*)d_in[8];
  const float* gm = (const float*)d_in[9];
  float* outp = (float*)d_out;

  // ---- input sanity ----
  {
    int bad = -1;
    if (n_in < 10) bad = 12;
    else {
      const int expct[10] = {2048, 16384000, 512, 512, 33554432, 33554432,
                             65536, 8388608, 3, 1};
      for (int i = 0; i < 10; ++i)
        if (in_sizes[i] != expct[i]) { bad = i; break; }
    }
    if (bad < 0 && out_size != 67635200) bad = 13;
    if (bad >= 0) {
      diag_kernel<<<1, 64, 0, stream>>>(outp, 40960.f + (float)bad * 256.f, 7);
      return;
    }
  }

  char* ws = (char*)d_ws;
  size_t off = 0;
  auto nxt = [&](size_t b) { size_t r = off; off += (b + 255) & ~(size_t)255; return r; };
  u16* xb16 = (u16*)(ws + nxt(514UL * 4 * 512 * 2));
  u16* s1fb = (u16*)(ws + nxt(514UL * 4 * 512 * 2));
  u16* s1bb = (u16*)(ws + nxt(514UL * 4 * 512 * 2));
  u16* s2fb = (u16*)(ws + nxt(514UL * 4 * 512 * 2));
  u16* s2bb = (u16*)(ws + nxt(514UL * 4 * 512 * 2));
  u16* logitA = (u16*)(ws + nxt(2048UL * 512 * 2));
  unsigned* pbuf = (unsigned*)(ws + nxt(2UL * 2 * 64 * 1024 * 4));  // parity x dir x wg x 1024
  size_t sync_off = nxt(2UL * 512 * 4);                // 2 layers x 512 ints
  int* sync = (int*)(ws + sync_off);
  size_t sb_off = nxt(256);
  float* sb = (float*)(ws + sb_off);
  u16* XW = (u16*)(ws + nxt(2UL * 2056 * 16384 * 2));
  if (off > ws_size) {
    diag_kernel<<<1, 64, 0, stream>>>(outp, 49152.f, 7);
    return;
  }

  int errIdx = -1;
  hipError_t errE = hipSuccess;
  auto chk = [&](int idx) {
    hipError_t e = hipGetLastError();
    if (e != hipSuccess && errIdx < 0) { errIdx = idx; errE = e; }
  };

  hipMemsetAsync(ws + sync_off, 0, 2 * 512 * 4 + 256 + 256, stream);  // sync + sb

  embed_kernel<<<TT * 4, 256, 0, stream>>>(words, E, bos, eos, xb16, sb);
  chk(0);

  // ================= layer 0 =================
  xw_gemm<<<2 * 17 * 128, 256, 0, stream>>>(xb16, xb16, Win, bias, XW, sb, 0, 1);
  chk(1);
  scan_kernel<<<SCAN_WGS, SCAN_THR, 0, stream>>>(Wst, Wp, XW, s1fb, s1bb, pbuf,
                                                 sync, sb, 0, 2);
  chk(2);

  // ================= layer 1 =================
  xw_gemm<<<2 * 17 * 128, 256, 0, stream>>>(s1fb, s1bb, Win, bias, XW, sb, 1, 3);
  chk(3);
  scan_kernel<<<SCAN_WGS, SCAN_THR, 0, stream>>>(Wst, Wp, XW, s2fb, s2bb, pbuf,
                                                 sync + 512, sb, 1, 4);
  chk(4);

  mix_kernel<<<2048, 256, 0, stream>>>(xb16, s1fb, s1bb, s2fb, s2bb, sv, gm,
                                       outp, logitA, sb);
  chk(5);
  mask_fill<<<8, 256, 0, stream>>>(outp);
  chk(6);
  logit_gemm<<<4000, 256, 0, stream>>>(logitA, E, outp);
  chk(7);

  if (errIdx >= 0) {
    float code = 32768.f + (float)errIdx * 2048.f + (float)map_hip_err(errE) * 256.f;
    diag_kernel<<<1, 64, 0, stream>>>(outp, code, 7);
  }
  verify_kernel<<<1, 64, 0, stream>>>(sb, sync, outp);
}

// Round 20
// 11278.464 us; speedup vs baseline: 1.1923x; 1.1923x over previous
//
#include <hip/hip_runtime.h>
#include <cstdint>
#include <cstddef>

#define TT 514
#define DIR_WGS 64
#define SCAN_WGS 128
#define SCAN_THR 512

typedef unsigned short u16;
typedef unsigned long long u64;
typedef short short8 __attribute__((ext_vector_type(8)));
typedef float f32x4 __attribute__((ext_vector_type(4)));

__device__ __forceinline__ float bf2f(u16 u) {
  union { unsigned i; float f; } x; x.i = ((unsigned)u) << 16; return x.f;
}
__device__ __forceinline__ u16 f2bf(float f) {
  union { float f; unsigned i; } x; x.f = f;
  unsigned r = x.i + 0x7fffu + ((x.i >> 16) & 1u);
  return (u16)(r >> 16);
}
__device__ __forceinline__ float sigm(float x) { return 1.f / (1.f + expf(-x)); }
__device__ __forceinline__ f32x4 mfma16(short8 a, short8 b, f32x4 c) {
  return __builtin_amdgcn_mfma_f32_16x16x32_bf16(a, b, c, 0, 0, 0);
}
__device__ __forceinline__ void sb_set(float* sb, int k) {
  __hip_atomic_store(sb + k, 1.0f, __ATOMIC_RELAXED, __HIP_MEMORY_SCOPE_AGENT);
}

// distributed flag wait: lane l ACQUIRE-polls flags[l] (64 flags, 4 cachelines,
// parallel). Monotonic flags (= step+1). Dead check off the fast path.
__device__ __forceinline__ void wait_flags(int* flags, int target, int* dead) {
  if (threadIdx.x < 64) {
    int spins = 0;
    while (__hip_atomic_load(flags + threadIdx.x, __ATOMIC_ACQUIRE,
                             __HIP_MEMORY_SCOPE_AGENT) < target) {
      __builtin_amdgcn_s_sleep(1);
      if (((++spins) & 0xFFFF) == 0) {
        if (spins > (1 << 22) ||
            __hip_atomic_load(dead, __ATOMIC_RELAXED, __HIP_MEMORY_SCOPE_AGENT) != 0) {
          __hip_atomic_store(dead, 1, __ATOMIC_RELAXED, __HIP_MEMORY_SCOPE_AGENT);
          break;
        }
      }
    }
  }
  __syncthreads();
}

// ---- diagnostics (f32, visible) ----
__global__ void diag_kernel(float* __restrict__ out, float code, int slot) {
  if (threadIdx.x == 0 && blockIdx.x == 0) out[slot] = code;
}
__global__ void verify_kernel(const float* __restrict__ sb, const int* __restrict__ sync,
                              float* __restrict__ out) {
  if (threadIdx.x == 0 && blockIdx.x == 0) {
    for (int k = 0; k < 6; ++k) {
      float v = __hip_atomic_load(sb + k, __ATOMIC_RELAXED, __HIP_MEMORY_SCOPE_AGENT);
      if (v != 1.0f) out[9 + k] = 4096.f + (float)k * 256.f;
    }
    for (int l = 0; l < 2; ++l)
      for (int d = 0; d < 2; ++d)
        if (sync[l * 512 + d * 256 + 128] != 0)
          out[8] = 8192.f + (float)(l * 2 + d) * 256.f;
  }
}

// ---------------- embedding + BOS/EOS -> x bf16, layout [t][b][d] ----------------
__global__ __launch_bounds__(256) void embed_kernel(const int* __restrict__ words,
                                                    const float* __restrict__ E,
                                                    const float* __restrict__ bos,
                                                    const float* __restrict__ eos,
                                                    u16* __restrict__ xb16,
                                                    float* __restrict__ sb) {
  int bid = blockIdx.x;           // t*4 + b
  int t = bid >> 2, b = bid & 3;
  const float* src;
  if (t == 0) src = bos;
  else if (t == TT - 1) src = eos;
  else { int v = words[b * 512 + (t - 1)]; src = E + (size_t)v * 512; }
  for (int i = threadIdx.x; i < 512; i += 256)
    xb16[(size_t)bid * 512 + i] = f2bf(src[i]);
  if (bid == TT * 4 - 1 && threadIdx.x == 0) sb_set(sb, 0);
}

// ---- XW[dir][t*4+b][16384] = (x @ W_in + bias), bf16. K=512, M=2056, N=16384 ----
__global__ __launch_bounds__(256) void xw_gemm(const u16* __restrict__ Af,
                                               const u16* __restrict__ Ab,
                                               const float* __restrict__ Win_g,
                                               const float* __restrict__ bias_g,
                                               u16* __restrict__ XW,
                                               float* __restrict__ sb,
                                               int layer, int sbslot) {
  int bid = blockIdx.x;
  int dir = bid / (17 * 128);
  int rem = bid % (17 * 128);
  int mb = rem / 128, nb = rem % 128;
  const u16* A = dir ? Ab : Af;
  const float* B = Win_g + (size_t)(dir * 2 + layer) * 512 * 16384;
  const float* bias = bias_g + (size_t)(dir * 2 + layer) * 16384;
  u16* out = XW + (size_t)dir * 2056 * 16384;
  int m0 = mb * 128, n0 = nb * 128;
  __shared__ char lds[2 * 128 * 80];
  char* At = lds;
  char* Bt = lds + 128 * 80;
  int tid = threadIdx.x, wv = tid >> 6, ln = tid & 63;
  int wr = wv >> 1, wc = wv & 1;
  f32x4 acc[4][4];
  #pragma unroll
  for (int i = 0; i < 4; ++i)
    #pragma unroll
    for (int j = 0; j < 4; ++j) acc[i][j] = (f32x4){0.f, 0.f, 0.f, 0.f};
  for (int k0 = 0; k0 < 512; k0 += 32) {
    __syncthreads();
    {
      int r = tid >> 2, kq = (tid & 3) * 8;
      for (int rr = r; rr < 128; rr += 64) {
        int grow = m0 + rr; if (grow >= 2056) grow = 2055;
        short8 va = *(const short8*)(A + (size_t)grow * 512 + k0 + kq);
        *(short8*)(At + rr * 80 + kq * 2) = va;
      }
      int kk = tid >> 3, nq = (tid & 7) * 16;
      const float* bp = B + (size_t)(k0 + kk) * 16384 + n0 + nq;
      #pragma unroll
      for (int e = 0; e < 16; ++e)
        *(u16*)(Bt + (nq + e) * 80 + kk * 2) = f2bf(bp[e]);
    }
    __syncthreads();
    int lr = ln & 15, kq2 = (ln >> 4) * 8;
    short8 af[4], bf[4];
    #pragma unroll
    for (int i = 0; i < 4; ++i) {
      af[i] = *(const short8*)(At + (wr * 64 + i * 16 + lr) * 80 + kq2 * 2);
      bf[i] = *(const short8*)(Bt + (wc * 64 + i * 16 + lr) * 80 + kq2 * 2);
    }
    #pragma unroll
    for (int i = 0; i < 4; ++i)
      #pragma unroll
      for (int j = 0; j < 4; ++j) acc[i][j] = mfma16(af[i], bf[j], acc[i][j]);
  }
  int cc = ln & 15, rq = (ln >> 4) * 4;
  #pragma unroll
  for (int i = 0; i < 4; ++i)
    #pragma unroll
    for (int j = 0; j < 4; ++j) {
      int m = m0 + wr * 64 + i * 16 + rq;
      int v = n0 + wc * 64 + j * 16 + cc;
      float bv = bias[v];
      #pragma unroll
      for (int r2 = 0; r2 < 4; ++r2)
        if (m + r2 < 2056) out[(size_t)(m + r2) * 16384 + v] = f2bf(acc[i][j][r2] + bv);
    }
  if (bid == 2 * 17 * 128 - 1 && tid == 0) sb_set(sb, sbslot);
}

// ---------------- persistent bidirectional LSTM scan v18 (r16 + u64 paired reduce) ----------------
// 128 WGs x 512 thr. dir = wg>>6, wgd = wg&63 owns channels [wgd*64,+64).
// per step: gates (h LOCAL) -> a -> partial proj -> publish contiguous 4KB + flag ->
//   ONE wait -> each thread reduces slot-pair (2t,2t+1) via 64 u64 loads -> h local.
__global__ __launch_bounds__(SCAN_THR, 2) void scan_kernel(
    const float* __restrict__ Wst_g, const float* __restrict__ Wp_g,
    const u16* __restrict__ XW, u16* __restrict__ sob_f, u16* __restrict__ sob_b,
    unsigned* __restrict__ pbuf, int* __restrict__ sync, float* __restrict__ sb,
    int layer, int sbslot) {
  __shared__ u16 h_lds[4][520];          // stride 1040 B, local h (bf16)
  __shared__ float gates_lds[256][4];    // [col][b]
  __shared__ u16 a_loc[4][64];           // [b][ch] own channels
  int tid = threadIdx.x, ln = tid & 63;
  int wv = tid >> 6, l15 = ln & 15, lq = ln >> 4;
  int dir = (int)blockIdx.x >> 6, wgd = (int)blockIdx.x & 63;
  int dl = dir * 2 + layer;
  const float* Wst = Wst_g + (size_t)dl * 512 * 16384;
  const float* Wp  = Wp_g  + (size_t)dl * 4096 * 512;
  const u16* xw = XW + (size_t)dir * 2056 * 16384;
  u16* sob = dir ? sob_b : sob_f;
  int* pflags = sync + dir * 256;
  int* dead = pflags + 128;

  // W_state frags: 2 col-tiles x 16 k-tiles (this WG's 256 gate-cols)
  short8 wst[2][16];
  #pragma unroll
  for (int ct = 0; ct < 2; ++ct) {
    int colL = wv * 32 + ct * 16 + l15;
    int gcol = (colL >> 6) * 4096 + wgd * 64 + (colL & 63);
    #pragma unroll
    for (int kt = 0; kt < 16; ++kt) {
      short8 f;
      #pragma unroll
      for (int e = 0; e < 8; ++e)
        ((u16*)&f)[e] = f2bf(Wst[(size_t)(kt * 32 + lq * 8 + e) * 16384 + gcol]);
      wst[ct][kt] = f;
    }
  }
  // W_proj frags: own 64 channels (K=64, 2 k-tiles) x wave's 4 col-tiles (cols wv*64..+64)
  short8 wpf[4][2];
  #pragma unroll
  for (int ct = 0; ct < 4; ++ct) {
    #pragma unroll
    for (int kt = 0; kt < 2; ++kt) {
      short8 f;
      #pragma unroll
      for (int e = 0; e < 8; ++e)
        ((u16*)&f)[e] = f2bf(Wp[(size_t)(wgd * 64 + kt * 32 + lq * 8 + e) * 512 +
                                wv * 64 + ct * 16 + l15]);
      wpf[ct][kt] = f;
    }
  }
  float cst = 0.f;                       // c-state (tid<256): ch=tid>>2, b=tid&3
  int ew_ch = tid >> 2, ew_b = tid & 3;

  // zero local h(-1)
  for (int i = tid; i < 1040; i += SCAN_THR)
    *(unsigned*)((char*)h_lds + (i >> 8) * 1040 + (i & 255) * 4) = 0u;   // covers [4][512]

  // prefetch XW for step 0
  float xw0 = 0.f, xw1 = 0.f, xw2 = 0.f, xw3 = 0.f;
  if (tid < 256) {
    int t0 = dir ? (TT - 1) : 0;
    size_t xb0 = ((size_t)t0 * 4 + ew_b) * 16384 + wgd * 64 + ew_ch;
    xw0 = bf2f(xw[xb0]);        xw1 = bf2f(xw[xb0 + 4096]);
    xw2 = bf2f(xw[xb0 + 8192]); xw3 = bf2f(xw[xb0 + 12288]);
  }
  __syncthreads();

  for (int s = 0; s < TT; ++s) {
    int t = dir ? (TT - 1 - s) : s;
    // ---- P1: gates MFMA (h local in LDS) ----
    f32x4 g0 = {0.f, 0.f, 0.f, 0.f}, g1 = {0.f, 0.f, 0.f, 0.f};
    #pragma unroll
    for (int kt = 0; kt < 16; ++kt) {
      short8 hf = *(const short8*)((const char*)h_lds + (ln & 3) * 1040 + lq * 16 + kt * 64);
      g0 = mfma16(hf, wst[0][kt], g0);
      g1 = mfma16(hf, wst[1][kt], g1);
    }
    if (ln < 16) {
      #pragma unroll
      for (int r = 0; r < 4; ++r) {
        gates_lds[wv * 32 + l15][r] = g0[r];
        gates_lds[wv * 32 + 16 + l15][r] = g1[r];
      }
    }
    __syncthreads();
    // ---- P2: elementwise (prefetched XW) -> a (own 64 ch) ----
    if (tid < 256) {
      float gi = gates_lds[0 * 64 + ew_ch][ew_b] + xw0;
      float gf = gates_lds[1 * 64 + ew_ch][ew_b] + xw1;
      float gg = gates_lds[2 * 64 + ew_ch][ew_b] + xw2;
      float go = gates_lds[3 * 64 + ew_ch][ew_b] + xw3;
      float cn = sigm(gi) * tanhf(gg) + sigm(gf) * cst;
      cn = fminf(3.f, fmaxf(-3.f, cn));
      cst = cn;
      a_loc[ew_b][ew_ch] = f2bf(sigm(go) * tanhf(cn));
    }
    __syncthreads();
    // ---- P3: partial projection a[4x64] @ Wp[64x512] -> bf16 partials -> publish ----
    unsigned* pb = pbuf + (((s & 1) * 2) + dir) * 65536;   // [parity][dir][64wg][1024]
    {
      f32x4 pa[4];
      #pragma unroll
      for (int ct = 0; ct < 4; ++ct) {
        pa[ct] = (f32x4){0.f, 0.f, 0.f, 0.f};
        #pragma unroll
        for (int kt = 0; kt < 2; ++kt) {
          short8 af = *(const short8*)((const char*)a_loc + (ln & 3) * 128 + kt * 64 + lq * 16);
          pa[ct] = mfma16(af, wpf[ct][kt], pa[ct]);
        }
      }
      // D layout: col = wv*64 + ct*16 + (ln&15), rows 0..3 = regs (ln<16)
      unsigned* myp = pb + wgd * 1024;
      #pragma unroll
      for (int ct = 0; ct < 4; ++ct)
        #pragma unroll
        for (int r = 0; r < 4; ++r) {
          int pv = (int)f2bf(pa[ct][r]);
          int qv = __shfl_down(pv, 1, 64);   // neighbor col
          if (ln < 16 && (ln & 1) == 0) {
            int cp = (wv * 64 + ct * 16 + ln) >> 1;   // col-pair 0..255
            __hip_atomic_store(myp + r * 256 + cp,
                               (unsigned)(pv & 0xFFFF) | ((unsigned)qv << 16),
                               __ATOMIC_RELAXED, __HIP_MEMORY_SCOPE_AGENT);
          }
        }
    }
    __syncthreads();   // drain partial stores before flag
    if (tid == 0)
      __hip_atomic_store(pflags + wgd, s + 1, __ATOMIC_RELEASE, __HIP_MEMORY_SCOPE_AGENT);
    // prefetch XW for s+1 (independent; hides L3 latency under wait+reduce)
    if (s + 1 < TT && tid < 256) {
      int t1 = dir ? (TT - 2 - s) : (s + 1);
      size_t xb1 = ((size_t)t1 * 4 + ew_b) * 16384 + wgd * 64 + ew_ch;
      xw0 = bf2f(xw[xb1]);        xw1 = bf2f(xw[xb1 + 4096]);
      xw2 = bf2f(xw[xb1 + 8192]); xw3 = bf2f(xw[xb1 + 12288]);
    }
    // ---- P4: ONE wait, then reduce slot-pair (2t,2t+1) via 64 u64 loads -> h(s) ----
    wait_flags(pflags, s + 1, dead);
    {
      const u64* src64 = (const u64*)pb;   // u64 idx w*512 + tid = u32 idx w*1024 + 2t
      float lo0 = 0.f, hi0 = 0.f, lo1 = 0.f, hi1 = 0.f;
      #pragma unroll 8
      for (int w = 0; w < 64; ++w) {
        u64 v = __hip_atomic_load(src64 + w * 512 + tid, __ATOMIC_RELAXED,
                                  __HIP_MEMORY_SCOPE_AGENT);
        unsigned v0 = (unsigned)v, v1 = (unsigned)(v >> 32);
        lo0 += bf2f((u16)(v0 & 0xFFFF));
        hi0 += bf2f((u16)(v0 >> 16));
        lo1 += bf2f((u16)(v1 & 0xFFFF));
        hi1 += bf2f((u16)(v1 >> 16));
      }
      lo0 = fminf(3.f, fmaxf(-3.f, lo0));
      hi0 = fminf(3.f, fmaxf(-3.f, hi0));
      lo1 = fminf(3.f, fmaxf(-3.f, lo1));
      hi1 = fminf(3.f, fmaxf(-3.f, hi1));
      unsigned pk0 = (unsigned)f2bf(lo0) | ((unsigned)f2bf(hi0) << 16);
      unsigned pk1 = (unsigned)f2bf(lo1) | ((unsigned)f2bf(hi1) << 16);
      u64 pk = (u64)pk0 | ((u64)pk1 << 32);
      int q = tid * 2;                    // slots q, q+1: b = q>>8, cp = q&255 (even)
      int b = q >> 8, cp = q & 255;
      *(u64*)((char*)h_lds + b * 1040 + cp * 4) = pk;
      if (wgd == 0)
        *(u64*)(sob + ((size_t)t * 4 + b) * 512 + cp * 2) = pk;
    }
    __syncthreads();   // h(s) complete before next gates
  }
  if ((int)blockIdx.x == SCAN_WGS - 1 && tid == 0) sb_set(sb, sbslot);
}

// ------- softmax-weight mixing -> f32 output + bf16 logit A (tied=[E;E] K-fold) -------
__global__ __launch_bounds__(256) void mix_kernel(const u16* __restrict__ xb,
                                                  const u16* __restrict__ s1f,
                                                  const u16* __restrict__ s1b,
                                                  const u16* __restrict__ s2f,
                                                  const u16* __restrict__ s2b,
                                                  const float* __restrict__ sv,
                                                  const float* __restrict__ gm,
                                                  float* __restrict__ out,
                                                  u16* __restrict__ logitA,
                                                  float* __restrict__ sb) {
  int m = blockIdx.x;             // b*512 + tt
  int b = m >> 9, tt = m & 511;
  int t = tt + 1;
  float v0s = sv[0], v1s = sv[1], v2s = sv[2];
  float mx = fmaxf(v0s, fmaxf(v1s, v2s));
  float e0 = expf(v0s - mx), e1 = expf(v1s - mx), e2 = expf(v2s - mx);
  float inv = 1.f / (e0 + e1 + e2);
  float w0 = e0 * inv, w1 = e1 * inv, w2 = e2 * inv;
  float g = gm[0];
  size_t base = ((size_t)t * 4 + b) * 512;
  for (int d = threadIdx.x; d < 512; d += 256) {
    float xv = bf2f(xb[base + d]);
    float a1f = bf2f(s1f[base + d]), a1b = bf2f(s1b[base + d]);
    float a2f = bf2f(s2f[base + d]), a2b = bf2f(s2b[base + d]);
    float o0 = g * (w0 * xv + w1 * a1f + w2 * (a2f + a1f));  // layer2 = raw + layer1 resid
    float o1 = g * (w0 * xv + w1 * a1b + w2 * (a2b + a1b));
    out[(size_t)m * 1024 + d] = o0;
    out[(size_t)m * 1024 + 512 + d] = o1;
    logitA[(size_t)m * 512 + d] = f2bf(o0 + o1);
  }
  if (m == 2047 && threadIdx.x == 0) sb_set(sb, 5);
}

__global__ __launch_bounds__(256) void mask_fill(float* __restrict__ out) {
  int i = blockIdx.x * 256 + threadIdx.x;
  if (i < 2048) out[2097152 + i] = 1.0f;
}

// ---- logit GEMM: C[2048][32000](f32) = A[2048][512](bf16) * E[32000][512](f32->bf16)^T ----
__global__ __launch_bounds__(256) void logit_gemm(const u16* __restrict__ A,
                                                  const float* __restrict__ E,
                                                  float* __restrict__ out) {
  int bid = blockIdx.x;
  int mb = bid / 250, nb = bid % 250;
  int m0 = mb * 128, n0 = nb * 128;
  __shared__ char lds[2 * 128 * 80];
  char* At = lds;
  char* Bt = lds + 128 * 80;
  int tid = threadIdx.x, wv = tid >> 6, ln = tid & 63;
  int wr = wv >> 1, wc = wv & 1;
  f32x4 acc[4][4];
  #pragma unroll
  for (int i = 0; i < 4; ++i)
    #pragma unroll
    for (int j = 0; j < 4; ++j) acc[i][j] = (f32x4){0.f, 0.f, 0.f, 0.f};
  for (int k0 = 0; k0 < 512; k0 += 32) {
    __syncthreads();
    int r = tid >> 2, kq = (tid & 3) * 8;
    for (int rr = r; rr < 128; rr += 64) {
      short8 va = *(const short8*)(A + (size_t)(m0 + rr) * 512 + k0 + kq);
      *(short8*)(At + rr * 80 + kq * 2) = va;
      const float* ep = E + (size_t)(n0 + rr) * 512 + k0 + kq;
      float4 ea = *(const float4*)ep;
      float4 eb = *(const float4*)(ep + 4);
      short8 vb;
      ((u16*)&vb)[0] = f2bf(ea.x); ((u16*)&vb)[1] = f2bf(ea.y);
      ((u16*)&vb)[2] = f2bf(ea.z); ((u16*)&vb)[3] = f2bf(ea.w);
      ((u16*)&vb)[4] = f2bf(eb.x); ((u16*)&vb)[5] = f2bf(eb.y);
      ((u16*)&vb)[6] = f2bf(eb.z); ((u16*)&vb)[7] = f2bf(eb.w);
      *(short8*)(Bt + rr * 80 + kq * 2) = vb;
    }
    __syncthreads();
    int lr = ln & 15, kq2 = (ln >> 4) * 8;
    short8 af[4], bf[4];
    #pragma unroll
    for (int i = 0; i < 4; ++i) {
      af[i] = *(const short8*)(At + (wr * 64 + i * 16 + lr) * 80 + kq2 * 2);
      bf[i] = *(const short8*)(Bt + (wc * 64 + i * 16 + lr) * 80 + kq2 * 2);
    }
    #pragma unroll
    for (int i = 0; i < 4; ++i)
      #pragma unroll
      for (int j = 0; j < 4; ++j) acc[i][j] = mfma16(af[i], bf[j], acc[i][j]);
  }
  int cc = ln & 15, rq = (ln >> 4) * 4;
  #pragma unroll
  for (int i = 0; i < 4; ++i)
    #pragma unroll
    for (int j = 0; j < 4; ++j) {
      int m = m0 + wr * 64 + i * 16 + rq;
      int v = n0 + wc * 64 + j * 16 + cc;
      #pragma unroll
      for (int r2 = 0; r2 < 4; ++r2)
        out[2099200 + (size_t)(m + r2) * 32000 + v] = acc[i][j][r2];
    }
}

static int map_hip_err(hipError_t e) {
  switch ((int)e) {
    case 1: return 1;
    case 2: return 2;
    case 9: return 3;
    case 98: return 4;
    case 701: return 5;
    case 719: return 6;
    case 720: return 7;
    default: return 0;
  }
}

extern "C" void kernel_launch(void* const* d_in, const int* in_sizes, int n_in,
                              void* d_out, int out_size, void* d_ws, size_t ws_size,
                              hipStream_t stream) {
  const int* words = (const int*)d_in[0];
  const float* E = (const float*)d_in[1];
  const float* bos = (const float*)d_in[2];
  const float* eos = (const float*)d_in[3];
  const float* Win = (const float*)d_in[4];
  const float* Wst = (const float*)d_in[5];
  const float* bias = (const float*)d_in[6];
  const float* Wp = (const float*)d_in[7];
  const float* sv = (const float*)d_in[8];
  const float* gm = (const float*)d_in[9];
  float* outp = (float*)d_out;

  // ---- input sanity ----
  {
    int bad = -1;
    if (n_in < 10) bad = 12;
    else {
      const int expct[10] = {2048, 16384000, 512, 512, 33554432, 33554432,
                             65536, 8388608, 3, 1};
      for (int i = 0; i < 10; ++i)
        if (in_sizes[i] != expct[i]) { bad = i; break; }
    }
    if (bad < 0 && out_size != 67635200) bad = 13;
    if (bad >= 0) {
      diag_kernel<<<1, 64, 0, stream>>>(outp, 40960.f + (float)bad * 256.f, 7);
      return;
    }
  }

  char* ws = (char*)d_ws;
  size_t off = 0;
  auto nxt = [&](size_t b) { size_t r = off; off += (b + 255) & ~(size_t)255; return r; };
  u16* xb16 = (u16*)(ws + nxt(514UL * 4 * 512 * 2));
  u16* s1fb = (u16*)(ws + nxt(514UL * 4 * 512 * 2));
  u16* s1bb = (u16*)(ws + nxt(514UL * 4 * 512 * 2));
  u16* s2fb = (u16*)(ws + nxt(514UL * 4 * 512 * 2));
  u16* s2bb = (u16*)(ws + nxt(514UL * 4 * 512 * 2));
  u16* logitA = (u16*)(ws + nxt(2048UL * 512 * 2));
  unsigned* pbuf = (unsigned*)(ws + nxt(2UL * 2 * 64 * 1024 * 4));  // parity x dir x wg x 1024
  size_t sync_off = nxt(2UL * 512 * 4);                // 2 layers x 512 ints
  int* sync = (int*)(ws + sync_off);
  size_t sb_off = nxt(256);
  float* sb = (float*)(ws + sb_off);
  u16* XW = (u16*)(ws + nxt(2UL * 2056 * 16384 * 2));
  if (off > ws_size) {
    diag_kernel<<<1, 64, 0, stream>>>(outp, 49152.f, 7);
    return;
  }

  int errIdx = -1;
  hipError_t errE = hipSuccess;
  auto chk = [&](int idx) {
    hipError_t e = hipGetLastError();
    if (e != hipSuccess && errIdx < 0) { errIdx = idx; errE = e; }
  };

  hipMemsetAsync(ws + sync_off, 0, 2 * 512 * 4 + 256 + 256, stream);  // sync + sb

  embed_kernel<<<TT * 4, 256, 0, stream>>>(words, E, bos, eos, xb16, sb);
  chk(0);

  // ================= layer 0 =================
  xw_gemm<<<2 * 17 * 128, 256, 0, stream>>>(xb16, xb16, Win, bias, XW, sb, 0, 1);
  chk(1);
  scan_kernel<<<SCAN_WGS, SCAN_THR, 0, stream>>>(Wst, Wp, XW, s1fb, s1bb, pbuf,
                                                 sync, sb, 0, 2);
  chk(2);

  // ================= layer 1 =================
  xw_gemm<<<2 * 17 * 128, 256, 0, stream>>>(s1fb, s1bb, Win, bias, XW, sb, 1, 3);
  chk(3);
  scan_kernel<<<SCAN_WGS, SCAN_THR, 0, stream>>>(Wst, Wp, XW, s2fb, s2bb, pbuf,
                                                 sync + 512, sb, 1, 4);
  chk(4);

  mix_kernel<<<2048, 256, 0, stream>>>(xb16, s1fb, s1bb, s2fb, s2bb, sv, gm,
                                       outp, logitA, sb);
  chk(5);
  mask_fill<<<8, 256, 0, stream>>>(outp);
  chk(6);
  logit_gemm<<<4000, 256, 0, stream>>>(logitA, E, outp);
  chk(7);

  if (errIdx >= 0) {
    float code = 32768.f + (float)errIdx * 2048.f + (float)map_hip_err(errE) * 256.f;
    diag_kernel<<<1, 64, 0, stream>>>(outp, code, 7);
  }
  verify_kernel<<<1, 64, 0, stream>>>(sb, sync, outp);
}